// Round 8
// baseline (197.139 us; speedup 1.0000x reference)
//
#include <hip/hip_runtime.h>

#define HW 4096
#define LCAP 1536      // per-block hit list (expected ~80/block)

typedef short bf16x8 __attribute__((ext_vector_type(8)));
typedef float f32x16 __attribute__((ext_vector_type(16)));

__device__ __forceinline__ ushort f2bf_rne(float f) {
    unsigned u = __float_as_uint(f);
    return (ushort)((u + 0x7FFFu + ((u >> 16) & 1u)) >> 16);
}

// ---------------------------------------------------------------------------
// W transpose: Wt[c][o] = W[o][c].
// ---------------------------------------------------------------------------
__global__ __launch_bounds__(256) void transpose_w_kernel(
    const float* __restrict__ Wm, float* __restrict__ Wt)
{
    const int o = blockIdx.x;        // 128
    const int c = threadIdx.x;       // 256
    Wt[c * 128 + o] = Wm[o * 256 + c];
}

// ---------------------------------------------------------------------------
// Kernel 1: 1x1-conv projection, 8o x 8n register tile, v3.
// R7 forensics: v2's Xs[r][ng*8] read was 32B-stride -> 4-way bank conflict
// (2.77M conflicts), and grid 256 = 1 block/CU left staging latency exposed
// (Occupancy 9.5%, VALUBusy 33%).  v3: (a) thread's 8 n's split into two
// 4-wide groups at cols ng*4 and 64+ng*4 -> both ds_read_b128 at 16B stride
// (worst 2-way = free); (b) chunk cc+1 global->reg prefetch issued after the
// post-stage barrier, consumed at next LDS write -> HBM latency hides under
// the 64-r FMA block.  Per-output accumulation order (r=0..63, 4 sequential
// chunks, bias) UNCHANGED -> Qt/Pt/packs/qnorm bitwise identical; only the
// thread<->output assignment moved.
// Outputs: Qt/Pt fp32 [b][n][128], qnorm, bf16 packs in 32x32x16 fragment
// order: PK[b][t32][ks][lt][j] = proj[c=ks*16+(lt>>5)*8+j][n=t32*32+(lt&31)].
// ---------------------------------------------------------------------------
__global__ __launch_bounds__(256, 1) void proj_kernel(
    const float* __restrict__ Fq, const float* __restrict__ Fp,
    const float* __restrict__ Wt, const float* __restrict__ bias,
    float* __restrict__ Qt, float* __restrict__ Pt,
    ushort* __restrict__ Qpk, ushort* __restrict__ Ppk,
    float* __restrict__ qnorm)
{
    __shared__ float Ws[64][128];    // 32 KB: c-chunk x o
    __shared__ float Xs[64][128];    // 32 KB: c-chunk x n
    __shared__ float psum[16][137];  // 8.6 KB padded norm partials

    const int tid = threadIdx.x;
    const int z  = blockIdx.z;                 // 0: q, 1: p
    const float* __restrict__ X = z ? Fp : Fq;
    const int b  = blockIdx.y;
    const int n0 = blockIdx.x * 128;
    const int og = tid >> 4;                   // 0..15 -> o = og*8 .. +8
    const int ng = tid & 15;                   // n cols ng*4..+4 and 64+ng*4..+4

    float acc[8][8];                           // [n][o]; n: i<4 -> ng*4+i, else 64+ng*4+i-4
    #pragma unroll
    for (int i = 0; i < 8; ++i)
        #pragma unroll
        for (int j = 0; j < 8; ++j) acc[i][j] = 0.f;

    // prefetch chunk 0 into registers
    float4 wreg[8], xreg[8];
    {
        const float4* srcw = (const float4*)(Wt);
        #pragma unroll
        for (int it = 0; it < 8; ++it) wreg[it] = srcw[it * 256 + tid];
        #pragma unroll
        for (int it = 0; it < 8; ++it) {
            int f = it * 256 + tid;
            int r = f >> 5, n4 = f & 31;
            xreg[it] = *(const float4*)&X[(size_t)(b * 256 + r) * HW + n0 + n4 * 4];
        }
    }

    for (int cc = 0; cc < 4; ++cc) {
        __syncthreads();                       // prior chunk's reads done
        // write staged registers to LDS
        {
            float4* dst = (float4*)Ws;
            #pragma unroll
            for (int it = 0; it < 8; ++it) dst[it * 256 + tid] = wreg[it];
        }
        #pragma unroll
        for (int it = 0; it < 8; ++it) {
            int f = it * 256 + tid;
            int r = f >> 5, n4 = f & 31;
            *(float4*)&Xs[r][n4 * 4] = xreg[it];
        }
        __syncthreads();

        // issue next chunk's loads; they complete under the FMA block below
        if (cc < 3) {
            const float4* srcw = (const float4*)(Wt + (size_t)(cc + 1) * 64 * 128);
            #pragma unroll
            for (int it = 0; it < 8; ++it) wreg[it] = srcw[it * 256 + tid];
            #pragma unroll
            for (int it = 0; it < 8; ++it) {
                int f = it * 256 + tid;
                int r = f >> 5, n4 = f & 31;
                xreg[it] = *(const float4*)&X[(size_t)(b * 256 + (cc + 1) * 64 + r) * HW + n0 + n4 * 4];
            }
        }

        for (int r = 0; r < 64; ++r) {
            float4 w0 = *(const float4*)&Ws[r][og * 8];        // broadcast
            float4 w1 = *(const float4*)&Ws[r][og * 8 + 4];
            float4 x0 = *(const float4*)&Xs[r][ng * 4];        // 16B stride
            float4 x1 = *(const float4*)&Xs[r][64 + ng * 4];   // 16B stride
            float wa[8] = {w0.x, w0.y, w0.z, w0.w, w1.x, w1.y, w1.z, w1.w};
            float xa[8] = {x0.x, x0.y, x0.z, x0.w, x1.x, x1.y, x1.z, x1.w};
            #pragma unroll
            for (int i = 0; i < 8; ++i)
                #pragma unroll
                for (int j = 0; j < 8; ++j)
                    acc[i][j] += wa[j] * xa[i];
        }
    }

    // bias
    {
        float4 b0 = *(const float4*)&bias[og * 8];
        float4 b1 = *(const float4*)&bias[og * 8 + 4];
        float ba[8] = {b0.x, b0.y, b0.z, b0.w, b1.x, b1.y, b1.z, b1.w};
        #pragma unroll
        for (int i = 0; i < 8; ++i)
            #pragma unroll
            for (int j = 0; j < 8; ++j) acc[i][j] += ba[j];
    }

    // channel-sumsq partials -> full 128-channel sums per n
    #pragma unroll
    for (int i = 0; i < 8; ++i) {
        int col = (i < 4) ? (ng * 4 + i) : (64 + ng * 4 + i - 4);
        float s = 0.f;
        #pragma unroll
        for (int j = 0; j < 8; ++j) s += acc[i][j] * acc[i][j];
        psum[og][col] = s;
    }
    __syncthreads();
    float tot[8];
    #pragma unroll
    for (int i = 0; i < 8; ++i) {
        int col = (i < 4) ? (ng * 4 + i) : (64 + ng * 4 + i - 4);
        float s = 0.f;
        #pragma unroll
        for (int g = 0; g < 16; ++g) s += psum[g][col];
        tot[i] = s;
    }

    if (z) {   // normalize p over its 128 channels
        #pragma unroll
        for (int i = 0; i < 8; ++i) {
            float s = 1.0f / sqrtf(tot[i]);
            #pragma unroll
            for (int j = 0; j < 8; ++j) acc[i][j] *= s;
        }
    } else if (og == 0) {
        #pragma unroll
        for (int i = 0; i < 8; ++i) {
            int col = (i < 4) ? (ng * 4 + i) : (64 + ng * 4 + i - 4);
            qnorm[b * HW + n0 + col] = sqrtf(tot[i]);
        }
    }

    // fp32 transposed output for rescore
    {
        float* __restrict__ T = z ? Pt : Qt;
        #pragma unroll
        for (int i = 0; i < 8; ++i) {
            int col = (i < 4) ? (ng * 4 + i) : (64 + ng * 4 + i - 4);
            size_t tb = ((size_t)b * HW + n0 + col) * 128 + og * 8;
            *(float4*)&T[tb]     = make_float4(acc[i][0], acc[i][1], acc[i][2], acc[i][3]);
            *(float4*)&T[tb + 4] = make_float4(acc[i][4], acc[i][5], acc[i][6], acc[i][7]);
        }
    }
    // bf16 pack
    {
        ushort* __restrict__ PK = z ? Ppk : Qpk;
        const int ks = og >> 1;
        #pragma unroll
        for (int i = 0; i < 8; ++i) {
            int col = (i < 4) ? (ng * 4 + i) : (64 + ng * 4 + i - 4);
            const int na  = n0 + col;
            const int t32 = na >> 5;
            const int lt  = (na & 31) + 32 * (og & 1);
            ushort u[8];
            #pragma unroll
            for (int k = 0; k < 8; ++k) u[k] = f2bf_rne(acc[i][k]);
            size_t pk = ((((size_t)b * 128 + t32) * 8 + ks) * 64 + lt) * 8;
            uint4 w;
            w.x = (unsigned)u[0] | ((unsigned)u[1] << 16);
            w.y = (unsigned)u[2] | ((unsigned)u[3] << 16);
            w.z = (unsigned)u[4] | ((unsigned)u[5] << 16);
            w.w = (unsigned)u[6] | ((unsigned)u[7] << 16);
            *(uint4*)&PK[pk] = w;
        }
    }
}

// ---------------------------------------------------------------------------
// SINGLE sim pass: staged-B + register-Q, VALU tail deleted (unchanged R7).
// ---------------------------------------------------------------------------
__global__ __launch_bounds__(256, 4) void sim_sketch_kernel(
    const ushort* __restrict__ Qpk, const ushort* __restrict__ Ppk,
    const float* __restrict__ qnorm, unsigned char* __restrict__ SK)
{
    __shared__ ushort Bs[16384];   // 32 KB: 4 t32-rows of Ppk

    const int tid  = threadIdx.x;
    const int lane = tid & 63;
    const int w    = tid >> 6;
    const int nb   = blockIdx.x;
    const int b    = blockIdx.y;
    const int ms   = blockIdx.z;               // 0..31, 128 m's each
    const int hi   = lane >> 5;

    // stage B: t32-rows ms*4..+4 (32 KB), cooperative, coalesced
    {
        const uint4* src = (const uint4*)(Ppk + ((size_t)(b * 128 + ms * 4)) * 4096);
        uint4* dst = (uint4*)Bs;
        #pragma unroll
        for (int it = 0; it < 8; ++it) dst[it * 256 + tid] = src[it * 256 + tid];
    }

    // Q fragments: 8 x bf16x8 (32 VGPRs), loaded once, coalesced (L2-hit)
    const ushort* __restrict__ qbase =
        Qpk + ((size_t)(b * 128 + nb * 4)) * 4096 + (size_t)lane * 8;
    bf16x8 qf[8];
    #pragma unroll
    for (int ks = 0; ks < 8; ++ks)
        qf[ks] = *(const bf16x8*)(qbase + (w * 8 + ks) * 512);

    // per-n reciprocal scales
    float rq[16];
    #pragma unroll
    for (int r = 0; r < 16; ++r) {
        int nl_ = (r & 3) + 8 * (r >> 2) + 4 * hi;
        rq[r] = 256.0f / qnorm[b * HW + nb * 128 + w * 32 + nl_];
    }

    const size_t g16f = (size_t)b * 256 + (size_t)(nb * 4 + w) * 2 + hi;
    const int mb0 = ms * 128 + (lane & 31);

    __syncthreads();   // Bs ready

    #pragma unroll 2
    for (int mtl = 0; mtl < 4; ++mtl) {
        f32x16 acc;
        #pragma unroll
        for (int r = 0; r < 16; ++r) acc[r] = 0.f;
        #pragma unroll
        for (int ks = 0; ks < 8; ++ks) {
            bf16x8 bb = *(const bf16x8*)&Bs[((mtl * 8 + ks) * 64 + lane) * 8];
            acc = __builtin_amdgcn_mfma_f32_32x32x16_bf16(qf[ks], bb, acc, 0, 0, 0);
        }

        // quantize the 16 n-values of this m into one uint4
        unsigned dw[4] = {0u, 0u, 0u, 0u};
        #pragma unroll
        for (int r = 0; r < 16; ++r) {
            float x = acc[r] * rq[r];
#if __has_builtin(__builtin_amdgcn_cvt_pk_u8_f32)
            dw[r >> 2] = (unsigned)__builtin_amdgcn_cvt_pk_u8_f32(
                x, (unsigned)(r & 3), (int)dw[r >> 2]);
#else
            int vi = (int)rintf(x);
            vi = vi < 0 ? 0 : (vi > 255 ? 255 : vi);
            dw[r >> 2] |= (unsigned)vi << (8 * (r & 3));
#endif
        }
        const int m = mb0 + mtl * 32;
        uint4 pk;
        pk.x = dw[0]; pk.y = dw[1]; pk.z = dw[2]; pk.w = dw[3];
        *(uint4*)(SK + ((g16f * 4096 + (size_t)m) << 4)) = pk;
    }
}

// ---------------------------------------------------------------------------
// fused init + code-max threshold + scan + exact fp32 rescore (unchanged R7).
// t8[n] = maxcode[n] - 6; margin proof: code(m*) >= R(m*)*rq - 2.52 and
// maxcode <= R(m*)*rq + 2.52 => code(m*) >= maxcode - 6 always survives.
// ---------------------------------------------------------------------------
__device__ __noinline__ void dot_one_slow(
    const float* Qsrow, const float* __restrict__ Pt,
    int b, int m, int n, unsigned long long* __restrict__ best)
{
    const float4* __restrict__ pr = (const float4*)&Pt[((size_t)b * HW + m) * 128];
    float acc = 0.f;
    #pragma unroll
    for (int k = 0; k < 32; ++k) {
        float4 pv = pr[k];
        float4 qv = *(const float4*)&Qsrow[k * 4];
        acc += qv.x * pv.x + qv.y * pv.y + qv.z * pv.z + qv.w * pv.w;
    }
    unsigned u = __float_as_uint(acc);
    unsigned kk = (u & 0x80000000u) ? ~u : (u | 0x80000000u);
    unsigned long long key = ((unsigned long long)kk << 32) | (unsigned)(4095 - m);
    atomicMax(&best[(size_t)b * HW + n], key);
}

__global__ __launch_bounds__(256) void scan_rescore_kernel(
    const unsigned char* __restrict__ SK,
    const float* __restrict__ Qt, const float* __restrict__ Pt,
    unsigned long long* __restrict__ best)
{
    __shared__ float Qs[16][132];
    __shared__ int nlist[16];
    __shared__ int wmax[4][16];
    __shared__ int t8s[16];
    __shared__ ushort hl[LCAP];
    __shared__ unsigned lcnt;

    const int fg  = blockIdx.x;               // b*256 + g16
    const int tid = threadIdx.x;
    const int b = fg >> 8, g = fg & 255, t = g >> 1, gs = g & 1;
    const int wv_ = tid >> 6;

    if (tid == 0) lcnt = 0u;
    if (tid < 16) {
        int n = t * 32 + (tid & 3) + 8 * (tid >> 2) + 4 * gs;
        nlist[tid] = n;
        best[(size_t)b * HW + n] = 0ull;      // folded init: block-exclusive n
    }
    __syncthreads();

    #pragma unroll
    for (int it = 0; it < 2; ++it) {
        int idx = it * 256 + tid;
        int row = idx >> 5, c4 = (idx & 31) * 4;
        *(float4*)&Qs[row][c4] =
            *(const float4*)&Qt[((size_t)b * HW + nlist[row]) * 128 + c4];
    }

    const uint4* __restrict__ skrow = (const uint4*)(SK + ((size_t)fg << 16));

    // pass 1: per-n max code over all m
    int mx[16];
    #pragma unroll
    for (int j = 0; j < 16; ++j) mx[j] = 0;
    #pragma unroll 4
    for (int it = 0; it < 16; ++it) {
        uint4 v = skrow[it * 256 + tid];
        unsigned wv[4] = {v.x, v.y, v.z, v.w};
        #pragma unroll
        for (int d = 0; d < 4; ++d)
            #pragma unroll
            for (int k = 0; k < 4; ++k)
                mx[d * 4 + k] = max(mx[d * 4 + k], (int)((wv[d] >> (8 * k)) & 255u));
    }
    #pragma unroll
    for (int j = 0; j < 16; ++j) {
        int v = mx[j];
        #pragma unroll
        for (int d = 1; d < 64; d <<= 1)
            v = max(v, __shfl_xor(v, d, 64));
        mx[j] = v;
    }
    if ((tid & 63) == 0) {
        #pragma unroll
        for (int j = 0; j < 16; ++j) wmax[wv_][j] = mx[j];
    }
    __syncthreads();
    if (tid < 16) {
        int m0 = max(max(wmax[0][tid], wmax[1][tid]),
                     max(wmax[2][tid], wmax[3][tid]));
        int tt = m0 - 6;
        t8s[tid] = tt < 0 ? 0 : tt;
    }
    __syncthreads();

    int myt[16];
    #pragma unroll
    for (int j = 0; j < 16; ++j) myt[j] = t8s[j];

    // pass 2: gate + collect (row is L2-hot from pass 1)
    #pragma unroll 4
    for (int it = 0; it < 16; ++it) {
        const int m = it * 256 + tid;
        uint4 v = skrow[it * 256 + tid];
        unsigned wv[4] = {v.x, v.y, v.z, v.w};
        #pragma unroll
        for (int d = 0; d < 4; ++d) {
            #pragma unroll
            for (int k = 0; k < 4; ++k) {
                int bv = (int)((wv[d] >> (8 * k)) & 255u);
                int j = d * 4 + k;
                if (bv >= myt[j]) {
                    unsigned pos = atomicAdd(&lcnt, 1u);
                    if (pos < LCAP) {
                        hl[pos] = (ushort)((j << 12) | m);
                    } else {   // overflow: inline (rare/never)
                        dot_one_slow(&Qs[j][0], Pt, b, m, nlist[j], best);
                    }
                }
            }
        }
    }

    __syncthreads();
    unsigned cnt = lcnt < LCAP ? lcnt : LCAP;
    for (unsigned p = tid; p < cnt; p += 256) {
        int e = hl[p];
        int j = e >> 12, m = e & 4095;
        const float4* __restrict__ pr = (const float4*)&Pt[((size_t)b * HW + m) * 128];
        float acc = 0.f;
        #pragma unroll
        for (int k = 0; k < 32; ++k) {
            float4 pv = pr[k];
            float4 qv = *(const float4*)&Qs[j][k * 4];
            acc += qv.x * pv.x + qv.y * pv.y + qv.z * pv.z + qv.w * pv.w;
        }
        unsigned u = __float_as_uint(acc);
        unsigned kk = (u & 0x80000000u) ? ~u : (u | 0x80000000u);
        unsigned long long key = ((unsigned long long)kk << 32) | (unsigned)(4095 - m);
        atomicMax(&best[(size_t)b * HW + nlist[j]], key);
    }
}

// ---------------------------------------------------------------------------
// gather: out[b][c][n] = Fp[b][c][m(n)]; stage each 16 KB Fp row in LDS.
// ---------------------------------------------------------------------------
__global__ __launch_bounds__(256) void gather_kernel(
    const float* __restrict__ Fp, const unsigned long long* __restrict__ best,
    float* __restrict__ out)
{
    __shared__ float row[4096];
    const int blk = blockIdx.x;      // 1024 = 4b x 256c
    const int c = blk & 255;
    const int b = blk >> 8;
    const int tid = threadIdx.x;

    const float* __restrict__ src = Fp + ((size_t)b * 256 + c) * HW;
    #pragma unroll
    for (int it = 0; it < 4; ++it) {
        int f = it * 256 + tid;
        *(float4*)&row[f * 4] = *(const float4*)&src[f * 4];
    }
    __syncthreads();

    float* __restrict__ dst = out + ((size_t)b * 256 + c) * HW;
    #pragma unroll
    for (int it = 0; it < 16; ++it) {
        int n = it * 256 + tid;
        int m = 4095 - (int)(best[(size_t)b * HW + n] & 0xFFFull);
        dst[n] = row[m];
    }
}

extern "C" void kernel_launch(void* const* d_in, const int* in_sizes, int n_in,
                              void* d_out, int out_size, void* d_ws, size_t ws_size,
                              hipStream_t stream) {
    const float* Fq   = (const float*)d_in[0];
    const float* Fp   = (const float*)d_in[1];
    const float* Wm   = (const float*)d_in[2];
    const float* bias = (const float*)d_in[3];
    float* out = (float*)d_out;

    char* base = (char*)d_ws;
    float*  Qt    = (float*)(base);                               // 8 MB
    float*  Pt    = (float*)(base + (8u << 20));                  // 8 MB
    ushort* Qpk   = (ushort*)(base + (16u << 20));                // 4 MB
    ushort* Ppk   = (ushort*)(base + (20u << 20));                // 4 MB
    unsigned char* SK = (unsigned char*)(base + (24u << 20));     // 64 MB
    char* x = base + (88u << 20);
    float*  qnorm = (float*)x;              x += 65536;           // 64 KB
    unsigned long long* best = (unsigned long long*)x; x += 131072; // 128 KB
    float*  Wtg   = (float*)x;                                    // 128 KB

    transpose_w_kernel<<<128, 256, 0, stream>>>(Wm, Wtg);
    proj_kernel<<<dim3(32, 4, 2), 256, 0, stream>>>(Fq, Fp, Wtg, bias,
                                                    Qt, Pt, Qpk, Ppk, qnorm);
    sim_sketch_kernel<<<dim3(32, 4, 32), 256, 0, stream>>>(Qpk, Ppk, qnorm, SK);
    scan_rescore_kernel<<<1024, 256, 0, stream>>>(SK, Qt, Pt, best);
    gather_kernel<<<1024, 256, 0, stream>>>(Fp, best, out);
}

// Round 9
// 168.751 us; speedup vs baseline: 1.1682x; 1.1682x over previous
//
#include <hip/hip_runtime.h>

#define HW 4096
#define LCAP 1536      // per-block hit list (expected ~80/block)

typedef short bf16x8 __attribute__((ext_vector_type(8)));
typedef float f32x16 __attribute__((ext_vector_type(16)));

__device__ __forceinline__ ushort f2bf_rne(float f) {
    unsigned u = __float_as_uint(f);
    return (ushort)((u + 0x7FFFu + ((u >> 16) & 1u)) >> 16);
}

// ---------------------------------------------------------------------------
// W transpose: Wt[c][o] = W[o][c].
// ---------------------------------------------------------------------------
__global__ __launch_bounds__(256) void transpose_w_kernel(
    const float* __restrict__ Wm, float* __restrict__ Wt)
{
    const int o = blockIdx.x;        // 128
    const int c = threadIdx.x;       // 256
    Wt[c * 128 + o] = Wm[o * 256 + c];
}

// ---------------------------------------------------------------------------
// Kernel 1: 1x1-conv projection — REVERTED to the original v1 (8o x 4n,
// 64-n tile, grid (64,4,2)=512 blocks).  R8 forensics: both "improved"
// projs were slower (v2: 4-way LDS bank conflict, 46us; v3: prefetch regs
// spilled to scratch, WRITE 24->73MB, 63-69us).  v1 never entered a top-5
// (<42us).  Accumulation order unchanged -> outputs bitwise-identical.
// Outputs: Qt/Pt fp32 [b][n][128], qnorm, bf16 packs in 32x32x16 fragment
// order: PK[b][t32][ks][lt][j] = proj[c=ks*16+(lt>>5)*8+j][n=t32*32+(lt&31)].
// ---------------------------------------------------------------------------
__global__ __launch_bounds__(256) void proj_kernel(
    const float* __restrict__ Fq, const float* __restrict__ Fp,
    const float* __restrict__ Wt, const float* __restrict__ bias,
    float* __restrict__ Qt, float* __restrict__ Pt,
    ushort* __restrict__ Qpk, ushort* __restrict__ Ppk,
    float* __restrict__ qnorm)
{
    __shared__ float Ws[64][128];    // 32 KB: c-chunk x o
    __shared__ float Xs[64][64];     // 16 KB: c-chunk x n
    __shared__ float psum[16][68];   // padded norm partials

    const int tid = threadIdx.x;
    const int z  = blockIdx.z;                 // 0: q, 1: p
    const float* __restrict__ X = z ? Fp : Fq;
    const int b  = blockIdx.y;
    const int n0 = blockIdx.x * 64;
    const int og = tid >> 4;                   // 0..15 -> o = og*8 .. +8
    const int ng = tid & 15;                   // 0..15 -> n = n0+ng*4 .. +4

    float acc[4][8];                           // [n][o]
    #pragma unroll
    for (int i = 0; i < 4; ++i)
        #pragma unroll
        for (int j = 0; j < 8; ++j) acc[i][j] = 0.f;

    for (int cc = 0; cc < 4; ++cc) {
        __syncthreads();                       // protect prior chunk's reads
        {
            const float4* src = (const float4*)(Wt + (size_t)cc * 64 * 128);
            float4* dst = (float4*)Ws;
            #pragma unroll
            for (int it = 0; it < 8; ++it) dst[it * 256 + tid] = src[it * 256 + tid];
        }
        #pragma unroll
        for (int it = 0; it < 4; ++it) {
            int f = it * 256 + tid;
            int r = f >> 4, n4 = f & 15;
            *(float4*)&Xs[r][n4 * 4] =
                *(const float4*)&X[(size_t)(b * 256 + cc * 64 + r) * HW + n0 + n4 * 4];
        }
        __syncthreads();

        for (int r = 0; r < 64; ++r) {
            float4 w0 = *(const float4*)&Ws[r][og * 8];
            float4 w1 = *(const float4*)&Ws[r][og * 8 + 4];
            float4 xv = *(const float4*)&Xs[r][ng * 4];
            float wa[8] = {w0.x, w0.y, w0.z, w0.w, w1.x, w1.y, w1.z, w1.w};
            float xa[4] = {xv.x, xv.y, xv.z, xv.w};
            #pragma unroll
            for (int i = 0; i < 4; ++i)
                #pragma unroll
                for (int j = 0; j < 8; ++j)
                    acc[i][j] += wa[j] * xa[i];
        }
    }

    {
        float4 b0 = *(const float4*)&bias[og * 8];
        float4 b1 = *(const float4*)&bias[og * 8 + 4];
        float ba[8] = {b0.x, b0.y, b0.z, b0.w, b1.x, b1.y, b1.z, b1.w};
        #pragma unroll
        for (int i = 0; i < 4; ++i)
            #pragma unroll
            for (int j = 0; j < 8; ++j) acc[i][j] += ba[j];
    }

    #pragma unroll
    for (int i = 0; i < 4; ++i) {
        float s = 0.f;
        #pragma unroll
        for (int j = 0; j < 8; ++j) s += acc[i][j] * acc[i][j];
        psum[og][ng * 4 + i] = s;
    }
    __syncthreads();
    float tot[4];
    #pragma unroll
    for (int i = 0; i < 4; ++i) {
        float s = 0.f;
        #pragma unroll
        for (int g = 0; g < 16; ++g) s += psum[g][ng * 4 + i];
        tot[i] = s;
    }

    if (z) {   // normalize p over its 128 channels
        #pragma unroll
        for (int i = 0; i < 4; ++i) {
            float s = 1.0f / sqrtf(tot[i]);
            #pragma unroll
            for (int j = 0; j < 8; ++j) acc[i][j] *= s;
        }
    } else if (og == 0) {
        #pragma unroll
        for (int i = 0; i < 4; ++i)
            qnorm[b * HW + n0 + ng * 4 + i] = sqrtf(tot[i]);
    }

    {
        float* __restrict__ T = z ? Pt : Qt;
        #pragma unroll
        for (int i = 0; i < 4; ++i) {
            size_t tb = ((size_t)b * HW + n0 + ng * 4 + i) * 128 + og * 8;
            *(float4*)&T[tb]     = make_float4(acc[i][0], acc[i][1], acc[i][2], acc[i][3]);
            *(float4*)&T[tb + 4] = make_float4(acc[i][4], acc[i][5], acc[i][6], acc[i][7]);
        }
    }
    {
        ushort* __restrict__ PK = z ? Ppk : Qpk;
        const int ks = og >> 1;
        #pragma unroll
        for (int i = 0; i < 4; ++i) {
            const int na  = n0 + ng * 4 + i;
            const int t32 = na >> 5;
            const int lt  = (na & 31) + 32 * (og & 1);
            ushort u[8];
            #pragma unroll
            for (int k = 0; k < 8; ++k) u[k] = f2bf_rne(acc[i][k]);
            size_t pk = ((((size_t)b * 128 + t32) * 8 + ks) * 64 + lt) * 8;
            uint4 w;
            w.x = (unsigned)u[0] | ((unsigned)u[1] << 16);
            w.y = (unsigned)u[2] | ((unsigned)u[3] << 16);
            w.z = (unsigned)u[4] | ((unsigned)u[5] << 16);
            w.w = (unsigned)u[6] | ((unsigned)u[7] << 16);
            *(uint4*)&PK[pk] = w;
        }
    }
}

// ---------------------------------------------------------------------------
// SINGLE sim pass: staged-B + register-Q + per-block max-code sidecar BM.
// BM[fg][ms][j] = max over this block's 128 m of code j (u8).  Exactness:
// codes = cvt(x) with cvt monotone, and max(cvt(x)) == cvt(max(x)); the
// running fp32 max + exact shuffle-max make BM bitwise equal to the max of
// the SK bytes it summarizes -> scan's t8 is IDENTICAL to the R7 two-pass
// result.  Tail cost (16 fmax/tile + 80 shuffle-max + 1 store) is smaller
// than R5's proven-42.6us Vmax+CM tail.  VGPR ~95 < 128 cap at (256,4).
// ---------------------------------------------------------------------------
__global__ __launch_bounds__(256, 4) void sim_sketch_kernel(
    const ushort* __restrict__ Qpk, const ushort* __restrict__ Ppk,
    const float* __restrict__ qnorm, unsigned char* __restrict__ SK,
    unsigned char* __restrict__ BM)
{
    __shared__ ushort Bs[16384];   // 32 KB: 4 t32-rows of Ppk

    const int tid  = threadIdx.x;
    const int lane = tid & 63;
    const int w    = tid >> 6;
    const int nb   = blockIdx.x;
    const int b    = blockIdx.y;
    const int ms   = blockIdx.z;               // 0..31, 128 m's each
    const int hi   = lane >> 5;

    // stage B: t32-rows ms*4..+4 (32 KB), cooperative, coalesced
    {
        const uint4* src = (const uint4*)(Ppk + ((size_t)(b * 128 + ms * 4)) * 4096);
        uint4* dst = (uint4*)Bs;
        #pragma unroll
        for (int it = 0; it < 8; ++it) dst[it * 256 + tid] = src[it * 256 + tid];
    }

    // Q fragments: 8 x bf16x8 (32 VGPRs), loaded once, coalesced (L2-hit)
    const ushort* __restrict__ qbase =
        Qpk + ((size_t)(b * 128 + nb * 4)) * 4096 + (size_t)lane * 8;
    bf16x8 qf[8];
    #pragma unroll
    for (int ks = 0; ks < 8; ++ks)
        qf[ks] = *(const bf16x8*)(qbase + (w * 8 + ks) * 512);

    // per-n reciprocal scales
    float rq[16];
    #pragma unroll
    for (int r = 0; r < 16; ++r) {
        int nl_ = (r & 3) + 8 * (r >> 2) + 4 * hi;
        rq[r] = 256.0f / qnorm[b * HW + nb * 128 + w * 32 + nl_];
    }

    const size_t g16f = (size_t)b * 256 + (size_t)(nb * 4 + w) * 2 + hi;
    const int mb0 = ms * 128 + (lane & 31);

    float xmax[16];
    #pragma unroll
    for (int r = 0; r < 16; ++r) xmax[r] = -1e30f;

    __syncthreads();   // Bs ready

    #pragma unroll 2
    for (int mtl = 0; mtl < 4; ++mtl) {
        f32x16 acc;
        #pragma unroll
        for (int r = 0; r < 16; ++r) acc[r] = 0.f;
        #pragma unroll
        for (int ks = 0; ks < 8; ++ks) {
            bf16x8 bb = *(const bf16x8*)&Bs[((mtl * 8 + ks) * 64 + lane) * 8];
            acc = __builtin_amdgcn_mfma_f32_32x32x16_bf16(qf[ks], bb, acc, 0, 0, 0);
        }

        // quantize the 16 n-values of this m into one uint4
        unsigned dw[4] = {0u, 0u, 0u, 0u};
        #pragma unroll
        for (int r = 0; r < 16; ++r) {
            float x = acc[r] * rq[r];
            xmax[r] = fmaxf(xmax[r], x);
#if __has_builtin(__builtin_amdgcn_cvt_pk_u8_f32)
            dw[r >> 2] = (unsigned)__builtin_amdgcn_cvt_pk_u8_f32(
                x, (unsigned)(r & 3), (int)dw[r >> 2]);
#else
            int vi = (int)rintf(x);
            vi = vi < 0 ? 0 : (vi > 255 ? 255 : vi);
            dw[r >> 2] |= (unsigned)vi << (8 * (r & 3));
#endif
        }
        const int m = mb0 + mtl * 32;
        uint4 pk;
        pk.x = dw[0]; pk.y = dw[1]; pk.z = dw[2]; pk.w = dw[3];
        *(uint4*)(SK + ((g16f * 4096 + (size_t)m) << 4)) = pk;
    }

    // cross-lane (32 m's) exact fp32 max, then the SAME cvt as the codes ->
    // BM byte == max of the 128 SK bytes it summarizes, bitwise.
    #pragma unroll
    for (int r = 0; r < 16; ++r) {
        float v = xmax[r];
        #pragma unroll
        for (int d = 1; d < 32; d <<= 1)
            v = fmaxf(v, __shfl_xor(v, d, 64));
        xmax[r] = v;
    }
    if ((lane & 31) == 0) {
        unsigned dw[4] = {0u, 0u, 0u, 0u};
        #pragma unroll
        for (int r = 0; r < 16; ++r) {
#if __has_builtin(__builtin_amdgcn_cvt_pk_u8_f32)
            dw[r >> 2] = (unsigned)__builtin_amdgcn_cvt_pk_u8_f32(
                xmax[r], (unsigned)(r & 3), (int)dw[r >> 2]);
#else
            int vi = (int)rintf(xmax[r]);
            vi = vi < 0 ? 0 : (vi > 255 ? 255 : vi);
            dw[r >> 2] |= (unsigned)vi << (8 * (r & 3));
#endif
        }
        uint4 pk;
        pk.x = dw[0]; pk.y = dw[1]; pk.z = dw[2]; pk.w = dw[3];
        *(uint4*)(BM + ((g16f * 32 + (size_t)ms) << 4)) = pk;
    }
}

// ---------------------------------------------------------------------------
// fused init + threshold-from-BM + scan + exact fp32 rescore.
// t8[n] = (max over 32 ms of BM) - 6 == R7's two-pass value, bitwise.
// Margin proof unchanged: code(m*) >= maxcode - 6 always survives; false
// hits killed by exact rescore.  Pass-1 over the 64 MB sketch is GONE.
// ---------------------------------------------------------------------------
__device__ __noinline__ void dot_one_slow(
    const float* Qsrow, const float* __restrict__ Pt,
    int b, int m, int n, unsigned long long* __restrict__ best)
{
    const float4* __restrict__ pr = (const float4*)&Pt[((size_t)b * HW + m) * 128];
    float acc = 0.f;
    #pragma unroll
    for (int k = 0; k < 32; ++k) {
        float4 pv = pr[k];
        float4 qv = *(const float4*)&Qsrow[k * 4];
        acc += qv.x * pv.x + qv.y * pv.y + qv.z * pv.z + qv.w * pv.w;
    }
    unsigned u = __float_as_uint(acc);
    unsigned kk = (u & 0x80000000u) ? ~u : (u | 0x80000000u);
    unsigned long long key = ((unsigned long long)kk << 32) | (unsigned)(4095 - m);
    atomicMax(&best[(size_t)b * HW + n], key);
}

__global__ __launch_bounds__(256) void scan_rescore_kernel(
    const unsigned char* __restrict__ SK, const unsigned char* __restrict__ BM,
    const float* __restrict__ Qt, const float* __restrict__ Pt,
    unsigned long long* __restrict__ best)
{
    __shared__ float Qs[16][132];
    __shared__ int nlist[16];
    __shared__ int t8s[16];
    __shared__ ushort hl[LCAP];
    __shared__ unsigned lcnt;

    const int fg  = blockIdx.x;               // b*256 + g16
    const int tid = threadIdx.x;
    const int b = fg >> 8, g = fg & 255, t = g >> 1, gs = g & 1;

    if (tid == 0) lcnt = 0u;
    if (tid < 16) {
        int n = t * 32 + (tid & 3) + 8 * (tid >> 2) + 4 * gs;
        nlist[tid] = n;
        best[(size_t)b * HW + n] = 0ull;      // folded init: block-exclusive n
        // threshold from the BM sidecar (512 B, replaces the 64 MB pass 1)
        const unsigned char* __restrict__ bmrow = BM + ((size_t)fg << 9);
        int mc = 0;
        #pragma unroll
        for (int ms = 0; ms < 32; ++ms)
            mc = max(mc, (int)bmrow[ms * 16 + tid]);
        int tt = mc - 6;
        t8s[tid] = tt < 0 ? 0 : tt;
    }
    __syncthreads();

    #pragma unroll
    for (int it = 0; it < 2; ++it) {
        int idx = it * 256 + tid;
        int row = idx >> 5, c4 = (idx & 31) * 4;
        *(float4*)&Qs[row][c4] =
            *(const float4*)&Qt[((size_t)b * HW + nlist[row]) * 128 + c4];
    }

    int myt[16];
    #pragma unroll
    for (int j = 0; j < 16; ++j) myt[j] = t8s[j];
    __syncthreads();   // Qs staged (inline-overflow dots read it)

    const uint4* __restrict__ skrow = (const uint4*)(SK + ((size_t)fg << 16));

    // single pass: gate bytes vs t8, collect hits
    #pragma unroll 4
    for (int it = 0; it < 16; ++it) {
        const int m = it * 256 + tid;
        uint4 v = skrow[it * 256 + tid];
        unsigned wv[4] = {v.x, v.y, v.z, v.w};
        #pragma unroll
        for (int d = 0; d < 4; ++d) {
            #pragma unroll
            for (int k = 0; k < 4; ++k) {
                int bv = (int)((wv[d] >> (8 * k)) & 255u);
                int j = d * 4 + k;
                if (bv >= myt[j]) {
                    unsigned pos = atomicAdd(&lcnt, 1u);
                    if (pos < LCAP) {
                        hl[pos] = (ushort)((j << 12) | m);
                    } else {   // overflow: inline (rare/never)
                        dot_one_slow(&Qs[j][0], Pt, b, m, nlist[j], best);
                    }
                }
            }
        }
    }

    __syncthreads();
    unsigned cnt = lcnt < LCAP ? lcnt : LCAP;
    for (unsigned p = tid; p < cnt; p += 256) {
        int e = hl[p];
        int j = e >> 12, m = e & 4095;
        const float4* __restrict__ pr = (const float4*)&Pt[((size_t)b * HW + m) * 128];
        float acc = 0.f;
        #pragma unroll
        for (int k = 0; k < 32; ++k) {
            float4 pv = pr[k];
            float4 qv = *(const float4*)&Qs[j][k * 4];
            acc += qv.x * pv.x + qv.y * pv.y + qv.z * pv.z + qv.w * pv.w;
        }
        unsigned u = __float_as_uint(acc);
        unsigned kk = (u & 0x80000000u) ? ~u : (u | 0x80000000u);
        unsigned long long key = ((unsigned long long)kk << 32) | (unsigned)(4095 - m);
        atomicMax(&best[(size_t)b * HW + nlist[j]], key);
    }
}

// ---------------------------------------------------------------------------
// gather: out[b][c][n] = Fp[b][c][m(n)]; stage each 16 KB Fp row in LDS.
// ---------------------------------------------------------------------------
__global__ __launch_bounds__(256) void gather_kernel(
    const float* __restrict__ Fp, const unsigned long long* __restrict__ best,
    float* __restrict__ out)
{
    __shared__ float row[4096];
    const int blk = blockIdx.x;      // 1024 = 4b x 256c
    const int c = blk & 255;
    const int b = blk >> 8;
    const int tid = threadIdx.x;

    const float* __restrict__ src = Fp + ((size_t)b * 256 + c) * HW;
    #pragma unroll
    for (int it = 0; it < 4; ++it) {
        int f = it * 256 + tid;
        *(float4*)&row[f * 4] = *(const float4*)&src[f * 4];
    }
    __syncthreads();

    float* __restrict__ dst = out + ((size_t)b * 256 + c) * HW;
    #pragma unroll
    for (int it = 0; it < 16; ++it) {
        int n = it * 256 + tid;
        int m = 4095 - (int)(best[(size_t)b * HW + n] & 0xFFFull);
        dst[n] = row[m];
    }
}

extern "C" void kernel_launch(void* const* d_in, const int* in_sizes, int n_in,
                              void* d_out, int out_size, void* d_ws, size_t ws_size,
                              hipStream_t stream) {
    const float* Fq   = (const float*)d_in[0];
    const float* Fp   = (const float*)d_in[1];
    const float* Wm   = (const float*)d_in[2];
    const float* bias = (const float*)d_in[3];
    float* out = (float*)d_out;

    char* base = (char*)d_ws;
    float*  Qt    = (float*)(base);                               // 8 MB
    float*  Pt    = (float*)(base + (8u << 20));                  // 8 MB
    ushort* Qpk   = (ushort*)(base + (16u << 20));                // 4 MB
    ushort* Ppk   = (ushort*)(base + (20u << 20));                // 4 MB
    unsigned char* SK = (unsigned char*)(base + (24u << 20));     // 64 MB
    char* x = base + (88u << 20);
    unsigned char* BM = (unsigned char*)x;  x += 524288;          // 512 KB
    float*  qnorm = (float*)x;              x += 65536;           // 64 KB
    unsigned long long* best = (unsigned long long*)x; x += 131072; // 128 KB
    float*  Wtg   = (float*)x;                                    // 128 KB

    transpose_w_kernel<<<128, 256, 0, stream>>>(Wm, Wtg);
    proj_kernel<<<dim3(64, 4, 2), 256, 0, stream>>>(Fq, Fp, Wtg, bias,
                                                    Qt, Pt, Qpk, Ppk, qnorm);
    sim_sketch_kernel<<<dim3(32, 4, 32), 256, 0, stream>>>(Qpk, Ppk, qnorm,
                                                           SK, BM);
    scan_rescore_kernel<<<1024, 256, 0, stream>>>(SK, BM, Qt, Pt, best);
    gather_kernel<<<1024, 256, 0, stream>>>(Fp, best, out);
}

// Round 10
// 166.246 us; speedup vs baseline: 1.1858x; 1.0151x over previous
//
#include <hip/hip_runtime.h>

#define HW 4096
#define LCAP 1536      // per-block hit list (expected ~80/block)

typedef short bf16x8 __attribute__((ext_vector_type(8)));
typedef float f32x16 __attribute__((ext_vector_type(16)));

__device__ __forceinline__ ushort f2bf_rne(float f) {
    unsigned u = __float_as_uint(f);
    return (ushort)((u + 0x7FFFu + ((u >> 16) & 1u)) >> 16);
}

// ---------------------------------------------------------------------------
// W transpose: Wt[c][o] = W[o][c].
// ---------------------------------------------------------------------------
__global__ __launch_bounds__(256) void transpose_w_kernel(
    const float* __restrict__ Wm, float* __restrict__ Wt)
{
    const int o = blockIdx.x;        // 128
    const int c = threadIdx.x;       // 256
    Wt[c * 128 + o] = Wm[o * 256 + c];
}

// ---------------------------------------------------------------------------
// Kernel 1: 1x1-conv projection (v1, frozen — R8 forensics: every "improved"
// variant was slower; v1 never entered a top-5).
// Outputs: Qt/Pt fp32 [b][n][128], qnorm, bf16 packs in 32x32x16 fragment
// order: PK[b][t32][ks][lt][j] = proj[c=ks*16+(lt>>5)*8+j][n=t32*32+(lt&31)].
// ---------------------------------------------------------------------------
__global__ __launch_bounds__(256) void proj_kernel(
    const float* __restrict__ Fq, const float* __restrict__ Fp,
    const float* __restrict__ Wt, const float* __restrict__ bias,
    float* __restrict__ Qt, float* __restrict__ Pt,
    ushort* __restrict__ Qpk, ushort* __restrict__ Ppk,
    float* __restrict__ qnorm)
{
    __shared__ float Ws[64][128];    // 32 KB: c-chunk x o
    __shared__ float Xs[64][64];     // 16 KB: c-chunk x n
    __shared__ float psum[16][68];   // padded norm partials

    const int tid = threadIdx.x;
    const int z  = blockIdx.z;                 // 0: q, 1: p
    const float* __restrict__ X = z ? Fp : Fq;
    const int b  = blockIdx.y;
    const int n0 = blockIdx.x * 64;
    const int og = tid >> 4;                   // 0..15 -> o = og*8 .. +8
    const int ng = tid & 15;                   // 0..15 -> n = n0+ng*4 .. +4

    float acc[4][8];                           // [n][o]
    #pragma unroll
    for (int i = 0; i < 4; ++i)
        #pragma unroll
        for (int j = 0; j < 8; ++j) acc[i][j] = 0.f;

    for (int cc = 0; cc < 4; ++cc) {
        __syncthreads();                       // protect prior chunk's reads
        {
            const float4* src = (const float4*)(Wt + (size_t)cc * 64 * 128);
            float4* dst = (float4*)Ws;
            #pragma unroll
            for (int it = 0; it < 8; ++it) dst[it * 256 + tid] = src[it * 256 + tid];
        }
        #pragma unroll
        for (int it = 0; it < 4; ++it) {
            int f = it * 256 + tid;
            int r = f >> 4, n4 = f & 15;
            *(float4*)&Xs[r][n4 * 4] =
                *(const float4*)&X[(size_t)(b * 256 + cc * 64 + r) * HW + n0 + n4 * 4];
        }
        __syncthreads();

        for (int r = 0; r < 64; ++r) {
            float4 w0 = *(const float4*)&Ws[r][og * 8];
            float4 w1 = *(const float4*)&Ws[r][og * 8 + 4];
            float4 xv = *(const float4*)&Xs[r][ng * 4];
            float wa[8] = {w0.x, w0.y, w0.z, w0.w, w1.x, w1.y, w1.z, w1.w};
            float xa[4] = {xv.x, xv.y, xv.z, xv.w};
            #pragma unroll
            for (int i = 0; i < 4; ++i)
                #pragma unroll
                for (int j = 0; j < 8; ++j)
                    acc[i][j] += wa[j] * xa[i];
        }
    }

    {
        float4 b0 = *(const float4*)&bias[og * 8];
        float4 b1 = *(const float4*)&bias[og * 8 + 4];
        float ba[8] = {b0.x, b0.y, b0.z, b0.w, b1.x, b1.y, b1.z, b1.w};
        #pragma unroll
        for (int i = 0; i < 4; ++i)
            #pragma unroll
            for (int j = 0; j < 8; ++j) acc[i][j] += ba[j];
    }

    #pragma unroll
    for (int i = 0; i < 4; ++i) {
        float s = 0.f;
        #pragma unroll
        for (int j = 0; j < 8; ++j) s += acc[i][j] * acc[i][j];
        psum[og][ng * 4 + i] = s;
    }
    __syncthreads();
    float tot[4];
    #pragma unroll
    for (int i = 0; i < 4; ++i) {
        float s = 0.f;
        #pragma unroll
        for (int g = 0; g < 16; ++g) s += psum[g][ng * 4 + i];
        tot[i] = s;
    }

    if (z) {   // normalize p over its 128 channels
        #pragma unroll
        for (int i = 0; i < 4; ++i) {
            float s = 1.0f / sqrtf(tot[i]);
            #pragma unroll
            for (int j = 0; j < 8; ++j) acc[i][j] *= s;
        }
    } else if (og == 0) {
        #pragma unroll
        for (int i = 0; i < 4; ++i)
            qnorm[b * HW + n0 + ng * 4 + i] = sqrtf(tot[i]);
    }

    {
        float* __restrict__ T = z ? Pt : Qt;
        #pragma unroll
        for (int i = 0; i < 4; ++i) {
            size_t tb = ((size_t)b * HW + n0 + ng * 4 + i) * 128 + og * 8;
            *(float4*)&T[tb]     = make_float4(acc[i][0], acc[i][1], acc[i][2], acc[i][3]);
            *(float4*)&T[tb + 4] = make_float4(acc[i][4], acc[i][5], acc[i][6], acc[i][7]);
        }
    }
    {
        ushort* __restrict__ PK = z ? Ppk : Qpk;
        const int ks = og >> 1;
        #pragma unroll
        for (int i = 0; i < 4; ++i) {
            const int na  = n0 + ng * 4 + i;
            const int t32 = na >> 5;
            const int lt  = (na & 31) + 32 * (og & 1);
            ushort u[8];
            #pragma unroll
            for (int k = 0; k < 8; ++k) u[k] = f2bf_rne(acc[i][k]);
            size_t pk = ((((size_t)b * 128 + t32) * 8 + ks) * 64 + lt) * 8;
            uint4 w;
            w.x = (unsigned)u[0] | ((unsigned)u[1] << 16);
            w.y = (unsigned)u[2] | ((unsigned)u[3] << 16);
            w.z = (unsigned)u[4] | ((unsigned)u[5] << 16);
            w.w = (unsigned)u[6] | ((unsigned)u[7] << 16);
            *(uint4*)&PK[pk] = w;
        }
    }
}

// ---------------------------------------------------------------------------
// SINGLE sim pass: staged-B + register-Q + BM sidecar (frozen from R8).
// BM[fg][ms][j] = max code over the block's 128 m (bitwise == max of the SK
// bytes it summarizes: cvt is monotone, shuffle-max exact).
// ---------------------------------------------------------------------------
__global__ __launch_bounds__(256, 4) void sim_sketch_kernel(
    const ushort* __restrict__ Qpk, const ushort* __restrict__ Ppk,
    const float* __restrict__ qnorm, unsigned char* __restrict__ SK,
    unsigned char* __restrict__ BM)
{
    __shared__ ushort Bs[16384];   // 32 KB: 4 t32-rows of Ppk

    const int tid  = threadIdx.x;
    const int lane = tid & 63;
    const int w    = tid >> 6;
    const int nb   = blockIdx.x;
    const int b    = blockIdx.y;
    const int ms   = blockIdx.z;               // 0..31, 128 m's each
    const int hi   = lane >> 5;

    // stage B: t32-rows ms*4..+4 (32 KB), cooperative, coalesced
    {
        const uint4* src = (const uint4*)(Ppk + ((size_t)(b * 128 + ms * 4)) * 4096);
        uint4* dst = (uint4*)Bs;
        #pragma unroll
        for (int it = 0; it < 8; ++it) dst[it * 256 + tid] = src[it * 256 + tid];
    }

    // Q fragments: 8 x bf16x8 (32 VGPRs), loaded once, coalesced (L2-hit)
    const ushort* __restrict__ qbase =
        Qpk + ((size_t)(b * 128 + nb * 4)) * 4096 + (size_t)lane * 8;
    bf16x8 qf[8];
    #pragma unroll
    for (int ks = 0; ks < 8; ++ks)
        qf[ks] = *(const bf16x8*)(qbase + (w * 8 + ks) * 512);

    // per-n reciprocal scales
    float rq[16];
    #pragma unroll
    for (int r = 0; r < 16; ++r) {
        int nl_ = (r & 3) + 8 * (r >> 2) + 4 * hi;
        rq[r] = 256.0f / qnorm[b * HW + nb * 128 + w * 32 + nl_];
    }

    const size_t g16f = (size_t)b * 256 + (size_t)(nb * 4 + w) * 2 + hi;
    const int mb0 = ms * 128 + (lane & 31);

    float xmax[16];
    #pragma unroll
    for (int r = 0; r < 16; ++r) xmax[r] = -1e30f;

    __syncthreads();   // Bs ready

    #pragma unroll 2
    for (int mtl = 0; mtl < 4; ++mtl) {
        f32x16 acc;
        #pragma unroll
        for (int r = 0; r < 16; ++r) acc[r] = 0.f;
        #pragma unroll
        for (int ks = 0; ks < 8; ++ks) {
            bf16x8 bb = *(const bf16x8*)&Bs[((mtl * 8 + ks) * 64 + lane) * 8];
            acc = __builtin_amdgcn_mfma_f32_32x32x16_bf16(qf[ks], bb, acc, 0, 0, 0);
        }

        // quantize the 16 n-values of this m into one uint4
        unsigned dw[4] = {0u, 0u, 0u, 0u};
        #pragma unroll
        for (int r = 0; r < 16; ++r) {
            float x = acc[r] * rq[r];
            xmax[r] = fmaxf(xmax[r], x);
#if __has_builtin(__builtin_amdgcn_cvt_pk_u8_f32)
            dw[r >> 2] = (unsigned)__builtin_amdgcn_cvt_pk_u8_f32(
                x, (unsigned)(r & 3), (int)dw[r >> 2]);
#else
            int vi = (int)rintf(x);
            vi = vi < 0 ? 0 : (vi > 255 ? 255 : vi);
            dw[r >> 2] |= (unsigned)vi << (8 * (r & 3));
#endif
        }
        const int m = mb0 + mtl * 32;
        uint4 pk;
        pk.x = dw[0]; pk.y = dw[1]; pk.z = dw[2]; pk.w = dw[3];
        *(uint4*)(SK + ((g16f * 4096 + (size_t)m) << 4)) = pk;
    }

    // cross-lane (32 m's) exact fp32 max, then the SAME cvt as the codes ->
    // BM byte == max of the 128 SK bytes it summarizes, bitwise.
    #pragma unroll
    for (int r = 0; r < 16; ++r) {
        float v = xmax[r];
        #pragma unroll
        for (int d = 1; d < 32; d <<= 1)
            v = fmaxf(v, __shfl_xor(v, d, 64));
        xmax[r] = v;
    }
    if ((lane & 31) == 0) {
        unsigned dw[4] = {0u, 0u, 0u, 0u};
        #pragma unroll
        for (int r = 0; r < 16; ++r) {
#if __has_builtin(__builtin_amdgcn_cvt_pk_u8_f32)
            dw[r >> 2] = (unsigned)__builtin_amdgcn_cvt_pk_u8_f32(
                xmax[r], (unsigned)(r & 3), (int)dw[r >> 2]);
#else
            int vi = (int)rintf(xmax[r]);
            vi = vi < 0 ? 0 : (vi > 255 ? 255 : vi);
            dw[r >> 2] |= (unsigned)vi << (8 * (r & 3));
#endif
        }
        uint4 pk;
        pk.x = dw[0]; pk.y = dw[1]; pk.z = dw[2]; pk.w = dw[3];
        *(uint4*)(BM + ((g16f * 32 + (size_t)ms) << 4)) = pk;
    }
}

// ---------------------------------------------------------------------------
// fused init + threshold-from-BM + SWAR scan + exact fp32 rescore.
// R9 change: the per-byte gate (16 extracts + 16 cmps + 16 divergent branch
// regions per uint4, over 64 MB) is replaced by an exact SWAR per-byte >=
// test, 6 ops/dword + ONE branch region per uint4:
//   GE_msb(x,y) = ((x & ~y) | (~(x^y) & ((x|H) - (y & ~H)))) & H, H=0x80..80
// Case check: xm>ym -> x&~y&H set; xm==ym -> L-term has MSB iff xl>=yl
// ((128+xl)-yl in [1,255], no cross-byte borrow); xm<ym -> 0.  Accept set is
// BIT-IDENTICAL to the byte loop -> candidates/absmax unchanged.
// t8[n] = (max over 32 ms of BM) - 6; margin proof unchanged.
// ---------------------------------------------------------------------------
__device__ __noinline__ void dot_one_slow(
    const float* Qsrow, const float* __restrict__ Pt,
    int b, int m, int n, unsigned long long* __restrict__ best)
{
    const float4* __restrict__ pr = (const float4*)&Pt[((size_t)b * HW + m) * 128];
    float acc = 0.f;
    #pragma unroll
    for (int k = 0; k < 32; ++k) {
        float4 pv = pr[k];
        float4 qv = *(const float4*)&Qsrow[k * 4];
        acc += qv.x * pv.x + qv.y * pv.y + qv.z * pv.z + qv.w * pv.w;
    }
    unsigned u = __float_as_uint(acc);
    unsigned kk = (u & 0x80000000u) ? ~u : (u | 0x80000000u);
    unsigned long long key = ((unsigned long long)kk << 32) | (unsigned)(4095 - m);
    atomicMax(&best[(size_t)b * HW + n], key);
}

__global__ __launch_bounds__(256) void scan_rescore_kernel(
    const unsigned char* __restrict__ SK, const unsigned char* __restrict__ BM,
    const float* __restrict__ Qt, const float* __restrict__ Pt,
    unsigned long long* __restrict__ best)
{
    __shared__ float Qs[16][132];
    __shared__ int nlist[16];
    __shared__ int t8s[16];
    __shared__ ushort hl[LCAP];
    __shared__ unsigned lcnt;

    const int fg  = blockIdx.x;               // b*256 + g16
    const int tid = threadIdx.x;
    const int b = fg >> 8, g = fg & 255, t = g >> 1, gs = g & 1;

    if (tid == 0) lcnt = 0u;
    if (tid < 16) {
        int n = t * 32 + (tid & 3) + 8 * (tid >> 2) + 4 * gs;
        nlist[tid] = n;
        best[(size_t)b * HW + n] = 0ull;      // folded init: block-exclusive n
        // threshold from the BM sidecar (512 B)
        const unsigned char* __restrict__ bmrow = BM + ((size_t)fg << 9);
        int mc = 0;
        #pragma unroll
        for (int ms = 0; ms < 32; ++ms)
            mc = max(mc, (int)bmrow[ms * 16 + tid]);
        int tt = mc - 6;
        t8s[tid] = tt < 0 ? 0 : tt;
    }
    __syncthreads();

    #pragma unroll
    for (int it = 0; it < 2; ++it) {
        int idx = it * 256 + tid;
        int row = idx >> 5, c4 = (idx & 31) * 4;
        *(float4*)&Qs[row][c4] =
            *(const float4*)&Qt[((size_t)b * HW + nlist[row]) * 128 + c4];
    }

    int myt[16];
    #pragma unroll
    for (int j = 0; j < 16; ++j) myt[j] = t8s[j];
    // packed threshold words: byte k of dword d <-> j = d*4+k (SK layout)
    unsigned tw[4];
    #pragma unroll
    for (int d = 0; d < 4; ++d)
        tw[d] = (unsigned)myt[d * 4]
              | ((unsigned)myt[d * 4 + 1] << 8)
              | ((unsigned)myt[d * 4 + 2] << 16)
              | ((unsigned)myt[d * 4 + 3] << 24);
    __syncthreads();   // Qs staged (inline-overflow dots read it)

    const uint4* __restrict__ skrow = (const uint4*)(SK + ((size_t)fg << 16));
    const unsigned H = 0x80808080u;

    // single pass: SWAR gate per uint4, decode only on (rare) hit
    #pragma unroll 4
    for (int it = 0; it < 16; ++it) {
        const int m = it * 256 + tid;
        uint4 v = skrow[it * 256 + tid];
        unsigned wv[4] = {v.x, v.y, v.z, v.w};
        unsigned ge[4];
        #pragma unroll
        for (int d = 0; d < 4; ++d) {
            unsigned x = wv[d], y = tw[d];
            unsigned L = (x | H) - (y & ~H);
            ge[d] = ((x & ~y) | (~(x ^ y) & L)) & H;
        }
        if (ge[0] | ge[1] | ge[2] | ge[3]) {
            #pragma unroll
            for (int d = 0; d < 4; ++d) {
                if (ge[d]) {
                    #pragma unroll
                    for (int k = 0; k < 4; ++k) {
                        if (ge[d] & (0x80u << (8 * k))) {
                            int j = d * 4 + k;
                            unsigned pos = atomicAdd(&lcnt, 1u);
                            if (pos < LCAP) {
                                hl[pos] = (ushort)((j << 12) | m);
                            } else {   // overflow: inline (rare/never)
                                dot_one_slow(&Qs[j][0], Pt, b, m, nlist[j], best);
                            }
                        }
                    }
                }
            }
        }
    }

    __syncthreads();
    unsigned cnt = lcnt < LCAP ? lcnt : LCAP;
    for (unsigned p = tid; p < cnt; p += 256) {
        int e = hl[p];
        int j = e >> 12, m = e & 4095;
        const float4* __restrict__ pr = (const float4*)&Pt[((size_t)b * HW + m) * 128];
        float acc = 0.f;
        #pragma unroll
        for (int k = 0; k < 32; ++k) {
            float4 pv = pr[k];
            float4 qv = *(const float4*)&Qs[j][k * 4];
            acc += qv.x * pv.x + qv.y * pv.y + qv.z * pv.z + qv.w * pv.w;
        }
        unsigned u = __float_as_uint(acc);
        unsigned kk = (u & 0x80000000u) ? ~u : (u | 0x80000000u);
        unsigned long long key = ((unsigned long long)kk << 32) | (unsigned)(4095 - m);
        atomicMax(&best[(size_t)b * HW + nlist[j]], key);
    }
}

// ---------------------------------------------------------------------------
// gather: out[b][c][n] = Fp[b][c][m(n)]; stage each 16 KB Fp row in LDS.
// ---------------------------------------------------------------------------
__global__ __launch_bounds__(256) void gather_kernel(
    const float* __restrict__ Fp, const unsigned long long* __restrict__ best,
    float* __restrict__ out)
{
    __shared__ float row[4096];
    const int blk = blockIdx.x;      // 1024 = 4b x 256c
    const int c = blk & 255;
    const int b = blk >> 8;
    const int tid = threadIdx.x;

    const float* __restrict__ src = Fp + ((size_t)b * 256 + c) * HW;
    #pragma unroll
    for (int it = 0; it < 4; ++it) {
        int f = it * 256 + tid;
        *(float4*)&row[f * 4] = *(const float4*)&src[f * 4];
    }
    __syncthreads();

    float* __restrict__ dst = out + ((size_t)b * 256 + c) * HW;
    #pragma unroll
    for (int it = 0; it < 16; ++it) {
        int n = it * 256 + tid;
        int m = 4095 - (int)(best[(size_t)b * HW + n] & 0xFFFull);
        dst[n] = row[m];
    }
}

extern "C" void kernel_launch(void* const* d_in, const int* in_sizes, int n_in,
                              void* d_out, int out_size, void* d_ws, size_t ws_size,
                              hipStream_t stream) {
    const float* Fq   = (const float*)d_in[0];
    const float* Fp   = (const float*)d_in[1];
    const float* Wm   = (const float*)d_in[2];
    const float* bias = (const float*)d_in[3];
    float* out = (float*)d_out;

    char* base = (char*)d_ws;
    float*  Qt    = (float*)(base);                               // 8 MB
    float*  Pt    = (float*)(base + (8u << 20));                  // 8 MB
    ushort* Qpk   = (ushort*)(base + (16u << 20));                // 4 MB
    ushort* Ppk   = (ushort*)(base + (20u << 20));                // 4 MB
    unsigned char* SK = (unsigned char*)(base + (24u << 20));     // 64 MB
    char* x = base + (88u << 20);
    unsigned char* BM = (unsigned char*)x;  x += 524288;          // 512 KB
    float*  qnorm = (float*)x;              x += 65536;           // 64 KB
    unsigned long long* best = (unsigned long long*)x; x += 131072; // 128 KB
    float*  Wtg   = (float*)x;                                    // 128 KB

    transpose_w_kernel<<<128, 256, 0, stream>>>(Wm, Wtg);
    proj_kernel<<<dim3(64, 4, 2), 256, 0, stream>>>(Fq, Fp, Wtg, bias,
                                                    Qt, Pt, Qpk, Ppk, qnorm);
    sim_sketch_kernel<<<dim3(32, 4, 32), 256, 0, stream>>>(Qpk, Ppk, qnorm,
                                                           SK, BM);
    scan_rescore_kernel<<<1024, 256, 0, stream>>>(SK, BM, Qt, Pt, best);
    gather_kernel<<<1024, 256, 0, stream>>>(Fp, best, out);
}